// Round 6
// baseline (484.884 us; speedup 1.0000x reference)
//
#include <hip/hip_runtime.h>

namespace {

constexpr float kAlpha = 0.025f;
constexpr float kC1 = 1.0e-4f;  // (0.01*1)^2
constexpr float kC2 = 9.0e-4f;  // (0.03*1)^2

constexpr int MPS = 72;  // mp row stride (shorts): 144 B, b128-aligned rows
constexpr int HTS = 68;  // hbT col stride (shorts): 136 B, b64-aligned

typedef __attribute__((ext_vector_type(8))) short short8;
typedef __attribute__((ext_vector_type(4))) float f32x4;

// LDS: mp 18,432 B + hbT 21,760 B + red 16 B ~= 40.2 KB -> 4 blocks/CU
struct __align__(16) Smem {
  short mp[2][64 * MPS];   // bf16 pixel maps: x, y
  short hbT[5][32 * HTS];  // bf16 H-conv results, transposed [out_col][row]
  float red[4];
};

union Frag {
  int i[4];
  int4 i4;
  short8 s8;
};

__device__ __forceinline__ unsigned f2bf(float f) {  // RNE fp32 -> bf16 bits
  unsigned u = __float_as_uint(f);
  return (u + 0x7FFFu + ((u >> 16) & 1u)) >> 16;
}
__device__ __forceinline__ unsigned pack2(float a, float b) {
  return f2bf(a) | (f2bf(b) << 16);
}
__device__ __forceinline__ float bfl(unsigned u) {  // low bf16 -> f32
  return __uint_as_float(u << 16);
}
__device__ __forceinline__ float bfh(unsigned u) {  // high bf16 -> f32
  return __uint_as_float(u & 0xFFFF0000u);
}

// elementwise synthesis of sq = x^2+y^2, xy, d = |x-y| fragments
template <bool WANT_D>
__device__ __forceinline__ void synth(const Frag& ax, const Frag& ay, Frag& sq,
                                      Frag& xy, Frag& dd) {
#pragma unroll
  for (int i = 0; i < 4; ++i) {
    unsigned ux = (unsigned)ax.i[i], uy = (unsigned)ay.i[i];
    float xl = bfl(ux), xh = bfh(ux), yl = bfl(uy), yh = bfh(uy);
    sq.i[i] = (int)pack2(fmaf(xl, xl, yl * yl), fmaf(xh, xh, yh * yh));
    xy.i[i] = (int)pack2(xl * yl, xh * yh);
    if (WANT_D) dd.i[i] = (int)pack2(fabsf(xl - yl), fabsf(xh - yh));
  }
}

// One sigma, full 33-tap band as banded matmul:
//  WH[k][n] = g[k-n], k-n in [0,32]; H(64x32) = In(64x64) x WH
//  WV = WH^T (same lane fragments);  Out(32x32) = WV(32x64) x H
template <bool LAST>
__device__ __forceinline__ void do_sigma(Smem& sm, const float* gmrow, int tid,
                                         f32x4& Pcs, f32x4& lumP, f32x4& l1v) {
  const int lane = tid & 63;
  const int w = tid >> 6;  // wave id
  const int quad = lane >> 4;
  const int l16 = lane & 15;

  // ---- build all 4 W fragments in registers (taps from global, L1-hot) ----
  const float rsc = rsqrtf(gmrow[16]);
  short8 wf[2][2];
#pragma unroll
  for (int nt = 0; nt < 2; ++nt)
#pragma unroll
    for (int kt = 0; kt < 2; ++kt) {
      Frag u;
#pragma unroll
      for (int p = 0; p < 4; ++p) {
        unsigned lh[2];
#pragma unroll
        for (int h = 0; h < 2; ++h) {
          int k = kt * 32 + quad * 8 + 2 * p + h;
          int idx = k - (nt * 16 + l16);  // tap index, valid [0,32]
          bool in = (idx >= 0) && (idx <= 32);
          int ic = min(max(idx, 0), 32);
          float g = gmrow[ic] * rsc;
          lh[h] = in ? f2bf(g) : 0u;
        }
        u.i[p] = (int)(lh[0] | (lh[1] << 16));
      }
      wf[nt][kt] = u.s8;
    }

  __syncthreads();  // B1: prev sigma's V reads of hbT done (patch at sigma 0)

  // ---- H GEMM: wave w owns mtile w (rows w*16..+16), all maps ----
  {
    const short* apx = sm.mp[0] + (w * 16 + l16) * MPS + quad * 8;
    const short* apy = sm.mp[1] + (w * 16 + l16) * MPS + quad * 8;
    Frag a[5][2];
    a[0][0].i4 = *(const int4*)(apx);
    a[0][1].i4 = *(const int4*)(apx + 32);
    a[1][0].i4 = *(const int4*)(apy);
    a[1][1].i4 = *(const int4*)(apy + 32);
#pragma unroll
    for (int half = 0; half < 2; ++half)
      synth<LAST>(a[0][half], a[1][half], a[2][half], a[3][half], a[4][half]);
#pragma unroll
    for (int m = 0; m < (LAST ? 5 : 4); ++m) {
#pragma unroll
      for (int nt = 0; nt < 2; ++nt) {
        f32x4 acc = {0.f, 0.f, 0.f, 0.f};
        acc = __builtin_amdgcn_mfma_f32_16x16x32_bf16(a[m][0].s8, wf[nt][0],
                                                      acc, 0, 0, 0);
        acc = __builtin_amdgcn_mfma_f32_16x16x32_bf16(a[m][1].s8, wf[nt][1],
                                                      acc, 0, 0, 0);
        // C/D: col=l16, row=quad*4+reg -> store transposed as bf16
        *(int2*)(&sm.hbT[m][(nt * 16 + l16) * HTS + w * 16 + quad * 4]) =
            make_int2((int)pack2(acc[0], acc[1]), (int)pack2(acc[2], acc[3]));
      }
    }
  }
  __syncthreads();  // B2: hbT ready

  // ---- V GEMM: wave quadrant (mtv = w>>1, ntv = w&1); A-frags = wf[mtv] ----
  const int mtv = w >> 1, ntv = w & 1;
  f32x4 va[LAST ? 5 : 4];
#pragma unroll
  for (int m = 0; m < (LAST ? 5 : 4); ++m) {
    const short* bp = sm.hbT[m] + (ntv * 16 + l16) * HTS + quad * 8;
    Frag b0, b1;
    *(int2*)&b0.i[0] = *(const int2*)(bp);
    *(int2*)&b0.i[2] = *(const int2*)(bp + 4);
    *(int2*)&b1.i[0] = *(const int2*)(bp + 32);
    *(int2*)&b1.i[2] = *(const int2*)(bp + 36);
    f32x4 acc = {0.f, 0.f, 0.f, 0.f};
    acc = __builtin_amdgcn_mfma_f32_16x16x32_bf16(wf[mtv][0], b0.s8, acc, 0, 0,
                                                  0);
    acc = __builtin_amdgcn_mfma_f32_16x16x32_bf16(wf[mtv][1], b1.s8, acc, 0, 0,
                                                  0);
    va[m] = acc;
  }

  // ---- combine in registers: pixel (mtv*16+quad*4+r, ntv*16+l16) ----
  float corr = 1.f;
  if (LAST) {  // fp32 tap-sum compensation for bf16-rounded weights
    float se = 0.f, st = 0.f;
#pragma unroll
    for (int j = 0; j < 33; ++j) {
      float g = gmrow[j] * rsc;
      se += g;
      st += bfl(f2bf(g));
    }
    float r1 = se / st;
    corr = r1 * r1;
  }
#pragma unroll
  for (int r = 0; r < 4; ++r) {
    float mux = va[0][r], muy = va[1][r], m2 = va[2][r], mxy = va[3][r];
    float mux2 = mux * mux, muy2 = muy * muy, muxy = mux * muy;
    float cs = (2.f * (mxy - muxy) + kC2) / ((m2 - mux2 - muy2) + kC2);
    Pcs[r] *= cs;
    if (LAST) {
      lumP[r] = ((2.f * muxy + kC1) / (mux2 + muy2 + kC1)) * Pcs[r];
      l1v[r] = va[4][r] * corr;
    }
  }
}

__global__ __launch_bounds__(256, 4) void msssim_l1_kernel(
    const float* __restrict__ x, const float* __restrict__ y,
    const float* __restrict__ gm, float* __restrict__ out) {
  __shared__ Smem sm;
  const int tid = threadIdx.x;

  // 64x64 halo patch, zero-padded; build bf16 x/y maps
  const float* xb = x + blockIdx.z * (512 * 512);
  const float* yb = y + blockIdx.z * (512 * 512);
  const int rb = blockIdx.y * 32 - 16;
  const int cb = blockIdx.x * 32 - 16;
  for (int f = tid; f < 1024; f += 256) {
    int pr = f >> 4;
    int pc = (f & 15) << 2;
    int gr = rb + pr, gc = cb + pc;
    float4 vx = make_float4(0.f, 0.f, 0.f, 0.f);
    float4 vy = vx;
    if (gr >= 0 && gr < 512 && gc >= 0 && gc < 512) {
      vx = *(const float4*)(xb + gr * 512 + gc);
      vy = *(const float4*)(yb + gr * 512 + gc);
    }
    const int base = pr * MPS + pc;  // shorts; byte offset 8-aligned
    *(int2*)(&sm.mp[0][base]) =
        make_int2((int)pack2(vx.x, vx.y), (int)pack2(vx.z, vx.w));
    *(int2*)(&sm.mp[1][base]) =
        make_int2((int)pack2(vy.x, vy.y), (int)pack2(vy.z, vy.w));
  }

  f32x4 Pcs = {1.f, 1.f, 1.f, 1.f};
  f32x4 lumP = {0.f, 0.f, 0.f, 0.f};
  f32x4 l1v = {0.f, 0.f, 0.f, 0.f};

  // taps: 1D row of each 2D mask; g[j] = m[16][j] / sqrt(m[16][16])
  const float* g0 = gm + 16 * 33;  // + s*1089
  do_sigma<false>(sm, g0 + 0 * 1089, tid, Pcs, lumP, l1v);
  do_sigma<false>(sm, g0 + 1 * 1089, tid, Pcs, lumP, l1v);
  do_sigma<false>(sm, g0 + 2 * 1089, tid, Pcs, lumP, l1v);
  do_sigma<false>(sm, g0 + 3 * 1089, tid, Pcs, lumP, l1v);
  do_sigma<true>(sm, g0 + 4 * 1089, tid, Pcs, lumP, l1v);

  // loss_mix = alpha*(1 - lum*PIcs) + (1-alpha)*gaussian_l1 ; out = 20*mean
  float lsum = 0.f;
#pragma unroll
  for (int r = 0; r < 4; ++r)
    lsum += kAlpha * (1.f - lumP[r]) + (1.f - kAlpha) * l1v[r];
#pragma unroll
  for (int off = 32; off > 0; off >>= 1) lsum += __shfl_down(lsum, off, 64);
  if ((tid & 63) == 0) sm.red[tid >> 6] = lsum;
  __syncthreads();
  if (tid == 0) {
    float t = sm.red[0] + sm.red[1] + sm.red[2] + sm.red[3];
    atomicAdd(out, t * (20.f / (16.f * 512.f * 512.f)));
  }
}

}  // namespace

extern "C" void kernel_launch(void* const* d_in, const int* in_sizes, int n_in,
                              void* d_out, int out_size, void* d_ws,
                              size_t ws_size, hipStream_t stream) {
  (void)in_sizes;
  (void)n_in;
  (void)d_ws;
  (void)ws_size;
  (void)out_size;
  const float* x = (const float*)d_in[0];
  const float* y = (const float*)d_in[1];
  const float* gm = (const float*)d_in[2];
  float* out = (float*)d_out;
  hipMemsetAsync(out, 0, sizeof(float), stream);
  dim3 grid(16, 16, 16);
  msssim_l1_kernel<<<grid, dim3(256), 0, stream>>>(x, y, gm, out);
}

// Round 7
// 335.563 us; speedup vs baseline: 1.4450x; 1.4450x over previous
//
#include <hip/hip_runtime.h>

namespace {

constexpr float kAlpha = 0.025f;
constexpr float kC1 = 1.0e-4f;  // (0.01*1)^2
constexpr float kC2 = 9.0e-4f;  // (0.03*1)^2

constexpr int MPS = 72;  // mp row stride (shorts): 144 B, b128-aligned rows
constexpr int HTS = 68;  // hbT col stride (shorts): 136 B, b64-aligned

typedef __attribute__((ext_vector_type(8))) short short8;
typedef __attribute__((ext_vector_type(4))) float f32x4;

// LDS: mp 18,432 B + hbT 21,760 B + red 16 B ~= 40.2 KB
struct __align__(16) Smem {
  short mp[2][64 * MPS];   // bf16 pixel maps: x, y
  short hbT[5][32 * HTS];  // bf16 H-conv results, transposed [out_col][row]
  float red[4];
};

union Frag {
  int i[4];
  int4 i4;
  short8 s8;
};

__device__ __forceinline__ unsigned f2bf(float f) {  // RNE fp32 -> bf16 bits
  unsigned u = __float_as_uint(f);
  return (u + 0x7FFFu + ((u >> 16) & 1u)) >> 16;
}
__device__ __forceinline__ unsigned pack2(float a, float b) {
  return f2bf(a) | (f2bf(b) << 16);
}
__device__ __forceinline__ float bfl(unsigned u) {  // low bf16 -> f32
  return __uint_as_float(u << 16);
}
__device__ __forceinline__ float bfh(unsigned u) {  // high bf16 -> f32
  return __uint_as_float(u & 0xFFFF0000u);
}

// synthesize map-m fragment from x/y fragments (m compile-time folded)
__device__ __forceinline__ Frag mkmap(int m, const Frag& ax, const Frag& ay) {
  if (m == 0) return ax;
  if (m == 1) return ay;
  Frag r;
#pragma unroll
  for (int i = 0; i < 4; ++i) {
    unsigned ux = (unsigned)ax.i[i], uy = (unsigned)ay.i[i];
    float xl = bfl(ux), xh = bfh(ux), yl = bfl(uy), yh = bfh(uy);
    if (m == 2)
      r.i[i] = (int)pack2(fmaf(xl, xl, yl * yl), fmaf(xh, xh, yh * yh));
    else if (m == 3)
      r.i[i] = (int)pack2(xl * yl, xh * yh);
    else
      r.i[i] = (int)pack2(fabsf(xl - yl), fabsf(xh - yh));
  }
  return r;
}

// One sigma, full 33-tap band as banded matmul:
//  WH[k][n] = g[k-n], k-n in [0,32]; H(64x32) = In(64x64) x WH
//  WV = WH^T (same lane fragments);  Out(32x32) = WV(32x64) x H
template <bool LAST>
__device__ __forceinline__ void do_sigma(Smem& sm, const float* gmrow, int tid,
                                         f32x4& Pcs, f32x4& lumP, f32x4& l1v) {
  const int lane = tid & 63;
  const int w = tid >> 6;  // wave id
  const int quad = lane >> 4;
  const int l16 = lane & 15;

  // ---- build all 4 W fragments in registers (taps from global, L1-hot) ----
  const float rsc = rsqrtf(gmrow[16]);
  short8 wf[2][2];
#pragma unroll
  for (int nt = 0; nt < 2; ++nt)
#pragma unroll
    for (int kt = 0; kt < 2; ++kt) {
      Frag u;
#pragma unroll
      for (int p = 0; p < 4; ++p) {
        unsigned lh[2];
#pragma unroll
        for (int h = 0; h < 2; ++h) {
          int k = kt * 32 + quad * 8 + 2 * p + h;
          int idx = k - (nt * 16 + l16);  // tap index, valid [0,32]
          bool in = (idx >= 0) && (idx <= 32);
          int ic = min(max(idx, 0), 32);
          float g = gmrow[ic] * rsc;
          lh[h] = in ? f2bf(g) : 0u;
        }
        u.i[p] = (int)(lh[0] | (lh[1] << 16));
      }
      wf[nt][kt] = u.s8;
    }

  __syncthreads();  // B1: prev sigma's V reads of hbT done (patch at sigma 0)

  // ---- H GEMM: wave w owns mtile w (rows w*16..+16), loops maps ----
  {
    const short* apx = sm.mp[0] + (w * 16 + l16) * MPS + quad * 8;
    const short* apy = sm.mp[1] + (w * 16 + l16) * MPS + quad * 8;
    Frag ax0, ax1, ay0, ay1;
    ax0.i4 = *(const int4*)(apx);
    ax1.i4 = *(const int4*)(apx + 32);
    ay0.i4 = *(const int4*)(apy);
    ay1.i4 = *(const int4*)(apy + 32);
#pragma unroll
    for (int m = 0; m < (LAST ? 5 : 4); ++m) {
      Frag f0 = mkmap(m, ax0, ay0);
      Frag f1 = mkmap(m, ax1, ay1);
#pragma unroll
      for (int nt = 0; nt < 2; ++nt) {
        f32x4 acc = {0.f, 0.f, 0.f, 0.f};
        acc = __builtin_amdgcn_mfma_f32_16x16x32_bf16(f0.s8, wf[nt][0], acc, 0,
                                                      0, 0);
        acc = __builtin_amdgcn_mfma_f32_16x16x32_bf16(f1.s8, wf[nt][1], acc, 0,
                                                      0, 0);
        // C/D: col=l16, row=quad*4+reg -> store transposed as bf16
        *(int2*)(&sm.hbT[m][(nt * 16 + l16) * HTS + w * 16 + quad * 4]) =
            make_int2((int)pack2(acc[0], acc[1]), (int)pack2(acc[2], acc[3]));
      }
    }
  }
  __syncthreads();  // B2: hbT ready

  // ---- V GEMM: wave quadrant (mtv = w>>1, ntv = w&1); A-frags = wf[mtv] ----
  const int mtv = w >> 1, ntv = w & 1;
  f32x4 va[LAST ? 5 : 4];
#pragma unroll
  for (int m = 0; m < (LAST ? 5 : 4); ++m) {
    const short* bp = sm.hbT[m] + (ntv * 16 + l16) * HTS + quad * 8;
    Frag b0, b1;
    *(int2*)&b0.i[0] = *(const int2*)(bp);
    *(int2*)&b0.i[2] = *(const int2*)(bp + 4);
    *(int2*)&b1.i[0] = *(const int2*)(bp + 32);
    *(int2*)&b1.i[2] = *(const int2*)(bp + 36);
    f32x4 acc = {0.f, 0.f, 0.f, 0.f};
    acc = __builtin_amdgcn_mfma_f32_16x16x32_bf16(wf[mtv][0], b0.s8, acc, 0, 0,
                                                  0);
    acc = __builtin_amdgcn_mfma_f32_16x16x32_bf16(wf[mtv][1], b1.s8, acc, 0, 0,
                                                  0);
    va[m] = acc;
  }

  // ---- combine in registers: pixel (mtv*16+quad*4+r, ntv*16+l16) ----
  float corr = 1.f;
  if (LAST) {  // fp32 tap-sum compensation for bf16-rounded weights
    float se = 0.f, st = 0.f;
#pragma unroll
    for (int j = 0; j < 33; ++j) {
      float g = gmrow[j] * rsc;
      se += g;
      st += bfl(f2bf(g));
    }
    float r1 = se / st;
    corr = r1 * r1;
  }
#pragma unroll
  for (int r = 0; r < 4; ++r) {
    float mux = va[0][r], muy = va[1][r], m2 = va[2][r], mxy = va[3][r];
    float mux2 = mux * mux, muy2 = muy * muy, muxy = mux * muy;
    float cs = (2.f * (mxy - muxy) + kC2) / ((m2 - mux2 - muy2) + kC2);
    Pcs[r] *= cs;
    if (LAST) {
      lumP[r] = ((2.f * muxy + kC1) / (mux2 + muy2 + kC1)) * Pcs[r];
      l1v[r] = va[4][r] * corr;
    }
  }
}

__global__ __launch_bounds__(256, 3) void msssim_l1_kernel(
    const float* __restrict__ x, const float* __restrict__ y,
    const float* __restrict__ gm, float* __restrict__ out) {
  __shared__ Smem sm;
  const int tid = threadIdx.x;

  // 64x64 halo patch, zero-padded; build bf16 x/y maps
  const float* xb = x + blockIdx.z * (512 * 512);
  const float* yb = y + blockIdx.z * (512 * 512);
  const int rb = blockIdx.y * 32 - 16;
  const int cb = blockIdx.x * 32 - 16;
  for (int f = tid; f < 1024; f += 256) {
    int pr = f >> 4;
    int pc = (f & 15) << 2;
    int gr = rb + pr, gc = cb + pc;
    float4 vx = make_float4(0.f, 0.f, 0.f, 0.f);
    float4 vy = vx;
    if (gr >= 0 && gr < 512 && gc >= 0 && gc < 512) {
      vx = *(const float4*)(xb + gr * 512 + gc);
      vy = *(const float4*)(yb + gr * 512 + gc);
    }
    const int base = pr * MPS + pc;  // shorts; byte offset 8-aligned
    *(int2*)(&sm.mp[0][base]) =
        make_int2((int)pack2(vx.x, vx.y), (int)pack2(vx.z, vx.w));
    *(int2*)(&sm.mp[1][base]) =
        make_int2((int)pack2(vy.x, vy.y), (int)pack2(vy.z, vy.w));
  }

  f32x4 Pcs = {1.f, 1.f, 1.f, 1.f};
  f32x4 lumP = {0.f, 0.f, 0.f, 0.f};
  f32x4 l1v = {0.f, 0.f, 0.f, 0.f};

  // taps: 1D row of each 2D mask; g[j] = m[16][j] / sqrt(m[16][16])
  const float* g0 = gm + 16 * 33;  // + s*1089
  do_sigma<false>(sm, g0 + 0 * 1089, tid, Pcs, lumP, l1v);
  do_sigma<false>(sm, g0 + 1 * 1089, tid, Pcs, lumP, l1v);
  do_sigma<false>(sm, g0 + 2 * 1089, tid, Pcs, lumP, l1v);
  do_sigma<false>(sm, g0 + 3 * 1089, tid, Pcs, lumP, l1v);
  do_sigma<true>(sm, g0 + 4 * 1089, tid, Pcs, lumP, l1v);

  // loss_mix = alpha*(1 - lum*PIcs) + (1-alpha)*gaussian_l1 ; out = 20*mean
  float lsum = 0.f;
#pragma unroll
  for (int r = 0; r < 4; ++r)
    lsum += kAlpha * (1.f - lumP[r]) + (1.f - kAlpha) * l1v[r];
#pragma unroll
  for (int off = 32; off > 0; off >>= 1) lsum += __shfl_down(lsum, off, 64);
  if ((tid & 63) == 0) sm.red[tid >> 6] = lsum;
  __syncthreads();
  if (tid == 0) {
    float t = sm.red[0] + sm.red[1] + sm.red[2] + sm.red[3];
    atomicAdd(out, t * (20.f / (16.f * 512.f * 512.f)));
  }
}

}  // namespace

extern "C" void kernel_launch(void* const* d_in, const int* in_sizes, int n_in,
                              void* d_out, int out_size, void* d_ws,
                              size_t ws_size, hipStream_t stream) {
  (void)in_sizes;
  (void)n_in;
  (void)d_ws;
  (void)ws_size;
  (void)out_size;
  const float* x = (const float*)d_in[0];
  const float* y = (const float*)d_in[1];
  const float* gm = (const float*)d_in[2];
  float* out = (float*)d_out;
  hipMemsetAsync(out, 0, sizeof(float), stream);
  dim3 grid(16, 16, 16);
  msssim_l1_kernel<<<grid, dim3(256), 0, stream>>>(x, y, gm, out);
}